// Round 1
// baseline (778.653 us; speedup 1.0000x reference)
//
#include <hip/hip_runtime.h>
#include <math.h>

#define EPSF 1e-8f
#define MT 32          // m (pixel) tile staged in LDS
#define CT 128         // channel rows per operand tile
#define MP 33          // padded LDS row stride (bank-conflict-free staging)

// ---------------- per-pixel inverse norms, all 4 tensors fused -------------
// pixel space: [x1t 16384][x1s 16384][x2t 4096][x2s 4096] = 40960
__global__ __launch_bounds__(256) void norm_kernel(
    const float* __restrict__ x1t, const float* __restrict__ x1s,
    const float* __restrict__ x2t, const float* __restrict__ x2s,
    float* __restrict__ invn)
{
    int gp = blockIdx.x * 64;   // 64 pixels per block, 4 channel-slices
    const float* x; int c, hw, base;
    if (gp < 16384)      { x = x1t; c = 128; hw = 4096; base = 0; }
    else if (gp < 32768) { x = x1s; c = 128; hw = 4096; base = 16384; }
    else if (gp < 36864) { x = x2t; c = 256; hw = 1024; base = 32768; }
    else                 { x = x2s; c = 256; hw = 1024; base = 36864; }
    int lane  = threadIdx.x & 63;
    int slice = threadIdx.x >> 6;
    int lp = gp - base + lane;           // local pixel within tensor
    int b = lp / hw, m = lp - b * hw;    // 64-pixel blocks never straddle b
    const float* p = x + ((size_t)b * c) * hw + m;
    int cs = c >> 2;
    float s = 0.f;
    for (int i = slice * cs; i < (slice + 1) * cs; ++i) {
        float v = p[(size_t)i * hw];
        s += v * v;
    }
    __shared__ float red[4][64];
    red[slice][lane] = s;
    __syncthreads();
    if (threadIdx.x < 64) {
        float tot = red[0][lane] + red[1][lane] + red[2][lane] + red[3][lane];
        invn[gp + lane] = 1.0f / (sqrtf(tot) + EPSF);
    }
}

// ---------------- c x c gram partials: G = (Fa) (Fb)^T ---------------------
// Fa[i,m] = xa[b,i,m] * invna[b,m].  Block computes a 128x128 sub-tile over
// one m-chunk, atomically accumulates into Gout[b][c][c].
__global__ __launch_bounds__(256) void gram_kernel(
    const float* __restrict__ xa, const float* __restrict__ xb,
    const float* __restrict__ wna, const float* __restrict__ wnb,
    float* __restrict__ Gout, int c, int hw, int chunk)
{
    __shared__ float ta[CT][MP];
    __shared__ float tb[CT][MP];

    const int b   = blockIdx.y;
    const int roa = (blockIdx.z >> 1) * 128;   // sub-tile row offsets (c=256)
    const int rob = (blockIdx.z & 1) * 128;
    const float* pa = xa + (size_t)(b * c + roa) * hw;
    const float* pb = xb + (size_t)(b * c + rob) * hw;
    const float* wa = wna + b * hw;
    const float* wb = wnb + b * hw;

    const int t  = threadIdx.x;
    const int ti = (t >> 4) << 3;   // 16 x 16 grid of 8x8 micro-tiles
    const int tj = (t & 15) << 3;
    const int sm = t & 31;          // staging: lane -> pixel (coalesced)
    const int si = t >> 5;          // staging: row slice 0..7

    float acc[8][8];
#pragma unroll
    for (int i = 0; i < 8; ++i)
#pragma unroll
        for (int j = 0; j < 8; ++j) acc[i][j] = 0.f;

    const int m_begin = blockIdx.x * chunk;
    for (int m0 = m_begin; m0 < m_begin + chunk; m0 += MT) {
        __syncthreads();
        {
            const int pm = m0 + sm;
            const float wA = wa[pm];
            const float wB = wb[pm];
#pragma unroll
            for (int k = 0; k < 16; ++k) {
                int i = si + (k << 3);
                ta[i][sm] = pa[(size_t)i * hw + pm] * wA;
                tb[i][sm] = pb[(size_t)i * hw + pm] * wB;
            }
        }
        __syncthreads();
#pragma unroll 2
        for (int m = 0; m < MT; ++m) {
            float av[8], bv[8];
#pragma unroll
            for (int k = 0; k < 8; ++k) av[k] = ta[ti + k][m];
#pragma unroll
            for (int k = 0; k < 8; ++k) bv[k] = tb[tj + k][m];
#pragma unroll
            for (int i = 0; i < 8; ++i)
#pragma unroll
                for (int j = 0; j < 8; ++j)
                    acc[i][j] += av[i] * bv[j];
        }
    }

    float* g = Gout + (size_t)b * c * c;
#pragma unroll
    for (int i = 0; i < 8; ++i)
#pragma unroll
        for (int j = 0; j < 8; ++j)
            atomicAdd(&g[(size_t)(roa + ti + i) * c + (rob + tj + j)], acc[i][j]);
}

// ---------------- Frobenius combination -> 4 scalars -----------------------
// grams layout: [g1: G11|G22|G12, each 4*128*128][g2: G11|G22|G12, each 4*256*256]
__global__ __launch_bounds__(256) void reduce_kernel(
    const float* __restrict__ grams, float* __restrict__ out)
{
    const int N1 = 3 * 4 * 128 * 128;   // 196608
    const int N2 = 3 * 4 * 256 * 256;   // 786432
    const float sc1 = 1.f / (4096.f * 4096.f * 4.f);
    const float sc2 = 1.f / (1024.f * 1024.f * 4.f);
    float s1 = 0.f, s2 = 0.f;
    for (int i = blockIdx.x * blockDim.x + threadIdx.x; i < N1 + N2;
         i += gridDim.x * blockDim.x) {
        float v = grams[i];
        float v2 = v * v;
        if (i < N1) {
            s1 += (i >= 2 * 4 * 128 * 128) ? -2.f * v2 : v2;   // G12 gets -2
        } else {
            int j = i - N1;
            s2 += (j >= 2 * 4 * 256 * 256) ? -2.f * v2 : v2;
        }
    }
    s1 *= sc1; s2 *= sc2;
    __shared__ float r1[256], r2[256];
    r1[threadIdx.x] = s1; r2[threadIdx.x] = s2;
    __syncthreads();
    for (int off = 128; off > 0; off >>= 1) {
        if (threadIdx.x < off) {
            r1[threadIdx.x] += r1[threadIdx.x + off];
            r2[threadIdx.x] += r2[threadIdx.x + off];
        }
        __syncthreads();
    }
    if (threadIdx.x == 0) {
        float g1 = r1[0], g2 = r2[0];
        atomicAdd(&out[0], g1 + g2);   // loss
        atomicAdd(&out[1], g1 + g2);   // stack[0] = loss
        atomicAdd(&out[2], g1);        // stack[1] = pwl_g1
        atomicAdd(&out[3], g2);        // stack[2] = pwl_g2
    }
}

extern "C" void kernel_launch(void* const* d_in, const int* in_sizes, int n_in,
                              void* d_out, int out_size, void* d_ws, size_t ws_size,
                              hipStream_t stream)
{
    const float* x1t = (const float*)d_in[0];   // [4,128,64,64]
    const float* x1s = (const float*)d_in[1];
    const float* x2t = (const float*)d_in[2];   // [4,256,32,32]
    const float* x2s = (const float*)d_in[3];

    float* ws    = (float*)d_ws;
    float* invn  = ws;                       // 40960 floats
    float* gram1 = ws + 40960;               // 196608 floats
    float* gram2 = ws + 40960 + 196608;      // 786432 floats
    float* out   = (float*)d_out;

    // zero gram accumulators + output (ws/out are poisoned before every call)
    hipMemsetAsync(gram1, 0, (196608 + 786432) * sizeof(float), stream);
    hipMemsetAsync(d_out, 0, 4 * sizeof(float), stream);

    norm_kernel<<<640, 256, 0, stream>>>(x1t, x1s, x2t, x2s, invn);

    // group 1: c=128, hw=4096, 16 m-chunks of 256 pixels
    dim3 g1(16, 4, 1);
    gram_kernel<<<g1, 256, 0, stream>>>(x1t, x1t, invn,         invn,         gram1,          128, 4096, 256);
    gram_kernel<<<g1, 256, 0, stream>>>(x1s, x1s, invn + 16384, invn + 16384, gram1 + 65536,  128, 4096, 256);
    gram_kernel<<<g1, 256, 0, stream>>>(x1t, x1s, invn,         invn + 16384, gram1 + 131072, 128, 4096, 256);

    // group 2: c=256, hw=1024, 8 m-chunks of 128 pixels, 4 output sub-tiles
    dim3 g2(8, 4, 4);
    gram_kernel<<<g2, 256, 0, stream>>>(x2t, x2t, invn + 32768, invn + 32768, gram2,          256, 1024, 128);
    gram_kernel<<<g2, 256, 0, stream>>>(x2s, x2s, invn + 36864, invn + 36864, gram2 + 262144, 256, 1024, 128);
    gram_kernel<<<g2, 256, 0, stream>>>(x2t, x2s, invn + 32768, invn + 36864, gram2 + 524288, 256, 1024, 128);

    reduce_kernel<<<512, 256, 0, stream>>>(gram1, out);
}

// Round 2
// 150.494 us; speedup vs baseline: 5.1740x; 5.1740x over previous
//
#include <hip/hip_runtime.h>
#include <math.h>

#define EPSF 1e-8f

typedef __attribute__((ext_vector_type(4))) short short4v;
typedef __attribute__((ext_vector_type(8))) short short8v;
typedef __attribute__((ext_vector_type(4))) float float4v;

__device__ inline short f2bf(float f) {
    unsigned u = __builtin_bit_cast(unsigned, f);
    unsigned r = (u + 0x7FFFu + ((u >> 16) & 1u)) >> 16;
    return (short)r;
}

// ---------------- per-pixel inverse norms, all 4 tensors fused -------------
// pixel space: [x1t 16384][x1s 16384][x2t 4096][x2s 4096] = 40960
__global__ __launch_bounds__(256) void norm_kernel(
    const float* __restrict__ x1t, const float* __restrict__ x1s,
    const float* __restrict__ x2t, const float* __restrict__ x2s,
    float* __restrict__ invn)
{
    int gp = blockIdx.x * 64;   // 64 pixels per block, 4 channel-slices
    const float* x; int c, hw, base;
    if (gp < 16384)      { x = x1t; c = 128; hw = 4096; base = 0; }
    else if (gp < 32768) { x = x1s; c = 128; hw = 4096; base = 16384; }
    else if (gp < 36864) { x = x2t; c = 256; hw = 1024; base = 32768; }
    else                 { x = x2s; c = 256; hw = 1024; base = 36864; }
    int lane  = threadIdx.x & 63;
    int slice = threadIdx.x >> 6;
    int lp = gp - base + lane;           // local pixel within tensor
    int b = lp / hw, m = lp - b * hw;    // 64-pixel blocks never straddle b
    const float* p = x + ((size_t)b * c) * hw + m;
    int cs = c >> 2;
    float s = 0.f;
    for (int i = slice * cs; i < (slice + 1) * cs; ++i) {
        float v = p[(size_t)i * hw];
        s += v * v;
    }
    __shared__ float red[4][64];
    red[slice][lane] = s;
    __syncthreads();
    if (threadIdx.x < 64) {
        float tot = red[0][lane] + red[1][lane] + red[2][lane] + red[3][lane];
        invn[gp + lane] = 1.0f / (sqrtf(tot) + EPSF);
    }
}

// ---------------- fused MFMA gram kernel -----------------------------------
// 384 blocks:
//   id <  192 : group1  (c=128, hw=4096)  g = id/64, b = (id%64)/16, ks = id%16
//   id >= 192 : group2  (c=256, hw=1024)  g, b, subtile st (2x2 of 128), ks%4
// Each block: 128x128 gram tile over a 256-pixel k-chunk, bf16 MFMA,
// atomicAdd fp32 partials into Gout.
__global__ __launch_bounds__(256) void gram_kernel(
    const float* __restrict__ x1t, const float* __restrict__ x1s,
    const float* __restrict__ x2t, const float* __restrict__ x2s,
    const float* __restrict__ invn,
    float* __restrict__ gram1, float* __restrict__ gram2)
{
    __shared__ short tile[2][128][68];   // +4 pad: 136B row stride

    const int id = blockIdx.x;
    const float *xt, *xs; const float *ivt, *ivs;
    float* Gout; int c, hw, roa, rob, m0base;
    int g, b;
    if (id < 192) {
        g = id >> 6; int rem = id & 63; b = rem >> 4; int ks = rem & 15;
        c = 128; hw = 4096; roa = 0; rob = 0; m0base = ks * 256;
        xt = x1t; xs = x1s; ivt = invn; ivs = invn + 16384;
        Gout = gram1 + (g * 4 + b) * 16384;
    } else {
        int id2 = id - 192;
        g = id2 >> 6; int rem = id2 & 63; b = rem >> 4; int q = rem & 15;
        int st = q >> 2; int ks = q & 3;
        c = 256; hw = 1024; roa = (st >> 1) * 128; rob = (st & 1) * 128;
        m0base = ks * 256;
        xt = x2t; xs = x2s; ivt = invn + 32768; ivs = invn + 36864;
        Gout = gram2 + (g * 4 + b) * 65536;
    }
    // gram type: 0 = t*t, 1 = s*s, 2 = t*s
    const float* xa  = (g == 1) ? xs  : xt;
    const float* xb  = (g == 0) ? xt  : xs;
    const float* iva = (g == 1) ? ivs : ivt;
    const float* ivb = (g == 0) ? ivt : ivs;

    const float* pa = xa + (size_t)(b * c + roa) * hw;
    const float* pb = xb + (size_t)(b * c + rob) * hw;
    const float* invA = iva + b * hw;
    const float* invB = ivb + b * hw;

    const int t    = threadIdx.x;
    const int mc   = t & 15;        // staging: 16B column within 64-px stage
    const int rb   = t >> 4;        // staging: base row 0..15
    const int lane = t & 63;
    const int w    = t >> 6;
    const int wr   = (w >> 1) * 64; // wave tile origin in 128x128
    const int wc   = (w & 1) * 64;
    const int r16  = lane & 15;
    const int quad = lane >> 4;

    float4v acc[4][4];
#pragma unroll
    for (int i = 0; i < 4; ++i)
#pragma unroll
        for (int j = 0; j < 4; ++j) acc[i][j] = (float4v){0.f, 0.f, 0.f, 0.f};

    for (int m0 = m0base; m0 < m0base + 256; m0 += 64) {
        __syncthreads();
        // ---- stage: fp32 global -> *invn -> bf16 -> LDS -------------------
        {
            const float4 wA = *(const float4*)(invA + m0 + mc * 4);
            const float4 wB = *(const float4*)(invB + m0 + mc * 4);
#pragma unroll
            for (int i = 0; i < 8; ++i) {
                int row = rb + i * 16;
                float4 v = *(const float4*)(pa + (size_t)row * hw + m0 + mc * 4);
                short4v s = { f2bf(v.x * wA.x), f2bf(v.y * wA.y),
                              f2bf(v.z * wA.z), f2bf(v.w * wA.w) };
                *(short4v*)&tile[0][row][mc * 4] = s;
            }
#pragma unroll
            for (int i = 0; i < 8; ++i) {
                int row = rb + i * 16;
                float4 v = *(const float4*)(pb + (size_t)row * hw + m0 + mc * 4);
                short4v s = { f2bf(v.x * wB.x), f2bf(v.y * wB.y),
                              f2bf(v.z * wB.z), f2bf(v.w * wB.w) };
                *(short4v*)&tile[1][row][mc * 4] = s;
            }
        }
        __syncthreads();
        // ---- MFMA over the 64 staged pixels: 2 k-steps of 32 --------------
#pragma unroll
        for (int kk = 0; kk < 2; ++kk) {
            const int kb = kk * 32 + quad * 8;   // bf16 units, 8B aligned
            short8v af[4], bf[4];
#pragma unroll
            for (int rt = 0; rt < 4; ++rt) {
                const short* p = &tile[0][wr + rt * 16 + r16][kb];
                short4v lo = *(const short4v*)p;
                short4v hi = *(const short4v*)(p + 4);
                af[rt] = (short8v){lo[0], lo[1], lo[2], lo[3],
                                   hi[0], hi[1], hi[2], hi[3]};
            }
#pragma unroll
            for (int ct = 0; ct < 4; ++ct) {
                const short* p = &tile[1][wc + ct * 16 + r16][kb];
                short4v lo = *(const short4v*)p;
                short4v hi = *(const short4v*)(p + 4);
                bf[ct] = (short8v){lo[0], lo[1], lo[2], lo[3],
                                   hi[0], hi[1], hi[2], hi[3]};
            }
#pragma unroll
            for (int rt = 0; rt < 4; ++rt)
#pragma unroll
                for (int ct = 0; ct < 4; ++ct)
                    acc[rt][ct] = __builtin_amdgcn_mfma_f32_16x16x32_bf16(
                        af[rt], bf[ct], acc[rt][ct], 0, 0, 0);
        }
    }

    // ---- epilogue: C/D layout col=lane&15, row=quad*4+reg -----------------
#pragma unroll
    for (int rt = 0; rt < 4; ++rt)
#pragma unroll
        for (int ct = 0; ct < 4; ++ct) {
            int col = rob + wc + ct * 16 + r16;
#pragma unroll
            for (int reg = 0; reg < 4; ++reg) {
                int row = roa + wr + rt * 16 + quad * 4 + reg;
                atomicAdd(&Gout[(size_t)row * c + col], acc[rt][ct][reg]);
            }
        }
}

// ---------------- Frobenius combination -> 4 scalars -----------------------
// grams layout: [g1: G11|G22|G12, each 4*128*128][g2: G11|G22|G12, each 4*256*256]
__global__ __launch_bounds__(256) void reduce_kernel(
    const float* __restrict__ grams, float* __restrict__ out)
{
    const int N1 = 3 * 4 * 128 * 128;   // 196608
    const int N2 = 3 * 4 * 256 * 256;   // 786432
    const float sc1 = 1.f / (4096.f * 4096.f * 4.f);
    const float sc2 = 1.f / (1024.f * 1024.f * 4.f);
    float s1 = 0.f, s2 = 0.f;
    for (int i = blockIdx.x * blockDim.x + threadIdx.x; i < N1 + N2;
         i += gridDim.x * blockDim.x) {
        float v = grams[i];
        float v2 = v * v;
        if (i < N1) {
            s1 += (i >= 2 * 4 * 128 * 128) ? -2.f * v2 : v2;   // G12 gets -2
        } else {
            int j = i - N1;
            s2 += (j >= 2 * 4 * 256 * 256) ? -2.f * v2 : v2;
        }
    }
    s1 *= sc1; s2 *= sc2;
    __shared__ float r1[256], r2[256];
    r1[threadIdx.x] = s1; r2[threadIdx.x] = s2;
    __syncthreads();
    for (int off = 128; off > 0; off >>= 1) {
        if (threadIdx.x < off) {
            r1[threadIdx.x] += r1[threadIdx.x + off];
            r2[threadIdx.x] += r2[threadIdx.x + off];
        }
        __syncthreads();
    }
    if (threadIdx.x == 0) {
        float g1 = r1[0], g2 = r2[0];
        atomicAdd(&out[0], g1 + g2);   // loss
        atomicAdd(&out[1], g1 + g2);   // stack[0] = loss
        atomicAdd(&out[2], g1);        // stack[1] = pwl_g1
        atomicAdd(&out[3], g2);        // stack[2] = pwl_g2
    }
}

extern "C" void kernel_launch(void* const* d_in, const int* in_sizes, int n_in,
                              void* d_out, int out_size, void* d_ws, size_t ws_size,
                              hipStream_t stream)
{
    const float* x1t = (const float*)d_in[0];   // [4,128,64,64]
    const float* x1s = (const float*)d_in[1];
    const float* x2t = (const float*)d_in[2];   // [4,256,32,32]
    const float* x2s = (const float*)d_in[3];

    float* ws    = (float*)d_ws;
    float* invn  = ws;                       // 40960 floats
    float* gram1 = ws + 40960;               // 196608 floats
    float* gram2 = ws + 40960 + 196608;      // 786432 floats
    float* out   = (float*)d_out;

    // zero gram accumulators + output (ws/out are poisoned before every call)
    hipMemsetAsync(gram1, 0, (196608 + 786432) * sizeof(float), stream);
    hipMemsetAsync(d_out, 0, 4 * sizeof(float), stream);

    norm_kernel<<<640, 256, 0, stream>>>(x1t, x1s, x2t, x2s, invn);

    gram_kernel<<<384, 256, 0, stream>>>(x1t, x1s, x2t, x2s, invn, gram1, gram2);

    reduce_kernel<<<512, 256, 0, stream>>>(gram1, out);
}

// Round 3
// 139.791 us; speedup vs baseline: 5.5701x; 1.0766x over previous
//
#include <hip/hip_runtime.h>
#include <math.h>

#define EPSF 1e-8f

typedef __attribute__((ext_vector_type(4))) short short4v;
typedef __attribute__((ext_vector_type(8))) short short8v;
typedef __attribute__((ext_vector_type(4))) float float4v;

__device__ inline short f2bf(float f) {
    unsigned u = __builtin_bit_cast(unsigned, f);
    unsigned r = (u + 0x7FFFu + ((u >> 16) & 1u)) >> 16;
    return (short)r;
}

// sub-tile tables: {g, ra64, rb64, wtcode}. g: 0=t*t 1=s*s 2=t*s.
// Diagonal grams (g<2) are symmetric: keep upper triangle, double off-diag.
__constant__ int g1_tab[10][4] = {
    {0,0,0,1},{0,0,1,2},{0,1,1,1},
    {1,0,0,1},{1,0,1,2},{1,1,1,1},
    {2,0,0,-2},{2,0,1,-2},{2,1,0,-2},{2,1,1,-2},
};
__constant__ int g2_tab[36][4] = {
    {0,0,0,1},{0,0,1,2},{0,0,2,2},{0,0,3,2},{0,1,1,1},{0,1,2,2},{0,1,3,2},{0,2,2,1},{0,2,3,2},{0,3,3,1},
    {1,0,0,1},{1,0,1,2},{1,0,2,2},{1,0,3,2},{1,1,1,1},{1,1,2,2},{1,1,3,2},{1,2,2,1},{1,2,3,2},{1,3,3,1},
    {2,0,0,-2},{2,0,1,-2},{2,0,2,-2},{2,0,3,-2},
    {2,1,0,-2},{2,1,1,-2},{2,1,2,-2},{2,1,3,-2},
    {2,2,0,-2},{2,2,1,-2},{2,2,2,-2},{2,2,3,-2},
    {2,3,0,-2},{2,3,1,-2},{2,3,2,-2},{2,3,3,-2},
};

// ---------------- per-pixel inverse norms, all 4 tensors fused -------------
// pixel space: [x1t 16384][x1s 16384][x2t 4096][x2s 4096] = 40960
// 320 blocks x 128 px; 8 channel-slices x 32 lanes, float4 loads (1KB/instr).
__global__ __launch_bounds__(256) void norm_kernel(
    const float* __restrict__ x1t, const float* __restrict__ x1s,
    const float* __restrict__ x2t, const float* __restrict__ x2s,
    float* __restrict__ invn)
{
    int gp = blockIdx.x * 128;
    const float* x; int c, hw, base;
    if (gp < 16384)      { x = x1t; c = 128; hw = 4096; base = 0; }
    else if (gp < 32768) { x = x1s; c = 128; hw = 4096; base = 16384; }
    else if (gp < 36864) { x = x2t; c = 256; hw = 1024; base = 32768; }
    else                 { x = x2s; c = 256; hw = 1024; base = 36864; }
    const int t = threadIdx.x;
    const int lanei = t & 31, slice = t >> 5;
    int lp = gp - base + lanei * 4;      // blocks never straddle b or tensor
    int b = lp / hw, m = lp - b * hw;
    const float* p = x + (size_t)b * c * hw + m;
    const int cpr = c >> 3;
    float4 s = {0.f, 0.f, 0.f, 0.f};
    for (int r = slice * cpr; r < (slice + 1) * cpr; ++r) {
        float4 v = *(const float4*)(p + (size_t)r * hw);
        s.x += v.x * v.x; s.y += v.y * v.y; s.z += v.z * v.z; s.w += v.w * v.w;
    }
    __shared__ float4 red[8][32];
    red[slice][lanei] = s;
    __syncthreads();
    if (t < 32) {
        float4 tot = {0.f, 0.f, 0.f, 0.f};
#pragma unroll
        for (int sl = 0; sl < 8; ++sl) {
            float4 v = red[sl][t];
            tot.x += v.x; tot.y += v.y; tot.z += v.z; tot.w += v.w;
        }
        float4 o = { 1.f / (sqrtf(tot.x) + EPSF), 1.f / (sqrtf(tot.y) + EPSF),
                     1.f / (sqrtf(tot.z) + EPSF), 1.f / (sqrtf(tot.w) + EPSF) };
        *(float4*)&invn[gp + t * 4] = o;
    }
}

// ---------------- gram-Frobenius kernel ------------------------------------
// 184 blocks; block = one 64x64 gram sub-tile over FULL k. 4 waves k-split,
// wave-private LDS staging (no barriers in k-loop), LDS combine, square,
// block-reduce -> one float per block. No global atomics, no memset needed.
__global__ __launch_bounds__(256) void gramfrob_kernel(
    const float* __restrict__ x1t, const float* __restrict__ x1s,
    const float* __restrict__ x2t, const float* __restrict__ x2s,
    const float* __restrict__ invn, float* __restrict__ partial)
{
    __shared__ __align__(16) char lds_raw[37888];
    short* tiles   = (short*)lds_raw;              // 4 waves x 2 x 64x36 sh = 36864 B
    float* redbuf  = (float*)lds_raw;              // 2 x 64x65 fl = 33280 B (aliases)
    float* scratch = (float*)(lds_raw + 36864);    // 256 fl

    int id = blockIdx.x;
    int c, hw, kPerWave, ra, rb, g, b; float wt;
    const float *xt, *xs, *ivt, *ivs;
    if (id < 40) {
        int comb = id >> 2; b = id & 3;
        g = g1_tab[comb][0]; ra = g1_tab[comb][1] << 6; rb = g1_tab[comb][2] << 6;
        wt = (float)g1_tab[comb][3] * (1.0f / (4096.f * 4096.f * 4.f));
        c = 128; hw = 4096; kPerWave = 1024;
        xt = x1t; xs = x1s; ivt = invn; ivs = invn + 16384;
    } else {
        int id2 = id - 40;
        int comb = id2 >> 2; b = id2 & 3;
        g = g2_tab[comb][0]; ra = g2_tab[comb][1] << 6; rb = g2_tab[comb][2] << 6;
        wt = (float)g2_tab[comb][3] * (1.0f / (1024.f * 1024.f * 4.f));
        c = 256; hw = 1024; kPerWave = 256;
        xt = x2t; xs = x2s; ivt = invn + 32768; ivs = invn + 36864;
    }
    const float* xa = (g == 1) ? xs : xt;
    const float* xb = (g == 0) ? xt : xs;
    const float* ia = ((g == 1) ? ivs : ivt) + b * hw;
    const float* ib = ((g == 0) ? ivt : ivs) + b * hw;
    const float* pa = xa + (size_t)(b * c + ra) * hw;
    const float* pb = xb + (size_t)(b * c + rb) * hw;
    const bool share = (g < 2) && (ra == rb);   // diagonal sub-tile: A==B

    const int t = threadIdx.x, w = t >> 6, lane = t & 63;
    const int r16 = lane & 15, quad = lane >> 4;
    const int srow = lane >> 3;          // staging row slice 0..7
    const int spx  = (lane & 7) << 2;    // staging px offset 0..28
    short* tA = tiles + w * 4608;
    short* tB = share ? tA : (tA + 2304);

    float4v acc[4][4];
#pragma unroll
    for (int i = 0; i < 4; ++i)
#pragma unroll
        for (int j = 0; j < 4; ++j) acc[i][j] = (float4v){0.f, 0.f, 0.f, 0.f};

    const int k0 = w * kPerWave;
    const int nIt = kPerWave >> 5;       // 32-px stages: g1->32, g2->8
    for (int it = 0; it < nIt; ++it) {
        const int px = k0 + (it << 5);
        {
            const float4 wA = *(const float4*)(ia + px + spx);
#pragma unroll
            for (int pass = 0; pass < 8; ++pass) {
                const int row = srow + (pass << 3);
                float4 v = *(const float4*)(pa + (size_t)row * hw + px + spx);
                short4v sv = { f2bf(v.x * wA.x), f2bf(v.y * wA.y),
                               f2bf(v.z * wA.z), f2bf(v.w * wA.w) };
                *(short4v*)&tA[row * 36 + spx] = sv;
            }
            if (!share) {
                const float4 wB = *(const float4*)(ib + px + spx);
#pragma unroll
                for (int pass = 0; pass < 8; ++pass) {
                    const int row = srow + (pass << 3);
                    float4 v = *(const float4*)(pb + (size_t)row * hw + px + spx);
                    short4v sv = { f2bf(v.x * wB.x), f2bf(v.y * wB.y),
                                   f2bf(v.z * wB.z), f2bf(v.w * wB.w) };
                    *(short4v*)&tB[row * 36 + spx] = sv;
                }
            }
        }
        __builtin_amdgcn_wave_barrier();   // wave-private LDS: in-order DS, no s_barrier
        {
            const int kb = quad << 3;
            short8v af[4], bfr[4];
#pragma unroll
            for (int rt = 0; rt < 4; ++rt) {
                const short* pp = &tA[(rt * 16 + r16) * 36 + kb];
                short4v lo = *(const short4v*)pp;
                short4v hi = *(const short4v*)(pp + 4);
                af[rt] = (short8v){lo[0], lo[1], lo[2], lo[3],
                                   hi[0], hi[1], hi[2], hi[3]};
            }
#pragma unroll
            for (int ct = 0; ct < 4; ++ct) {
                const short* pp = &tB[(ct * 16 + r16) * 36 + kb];
                short4v lo = *(const short4v*)pp;
                short4v hi = *(const short4v*)(pp + 4);
                bfr[ct] = (short8v){lo[0], lo[1], lo[2], lo[3],
                                    hi[0], hi[1], hi[2], hi[3]};
            }
#pragma unroll
            for (int rt = 0; rt < 4; ++rt)
#pragma unroll
                for (int ct = 0; ct < 4; ++ct)
                    acc[rt][ct] = __builtin_amdgcn_mfma_f32_16x16x32_bf16(
                        af[rt], bfr[ct], acc[rt][ct], 0, 0, 0);
        }
        __builtin_amdgcn_wave_barrier();
    }

    // ---- combine 4 wave partials in LDS, square, reduce -------------------
    __syncthreads();                      // tiles dead; redbuf aliases them
    float* regn = redbuf + (w & 1) * 4160;
    if (w < 2) {
#pragma unroll
        for (int rt = 0; rt < 4; ++rt)
#pragma unroll
            for (int ct = 0; ct < 4; ++ct)
#pragma unroll
                for (int r = 0; r < 4; ++r) {
                    int row = rt * 16 + quad * 4 + r;
                    int col = ct * 16 + r16;
                    regn[row * 65 + col] = acc[rt][ct][r];
                }
    }
    __syncthreads();
    if (w >= 2) {
#pragma unroll
        for (int rt = 0; rt < 4; ++rt)
#pragma unroll
            for (int ct = 0; ct < 4; ++ct)
#pragma unroll
                for (int r = 0; r < 4; ++r) {
                    int row = rt * 16 + quad * 4 + r;
                    int col = ct * 16 + r16;
                    regn[row * 65 + col] += acc[rt][ct][r];
                }
    }
    __syncthreads();
    float s = 0.f;
#pragma unroll
    for (int i = 0; i < 16; ++i) {
        int cell = (i << 8) + t;          // lane-stride-1: conflict-free
        int off = (cell >> 6) * 65 + (cell & 63);
        float v = redbuf[off] + redbuf[4160 + off];
        s += v * v;
    }
    s *= wt;                              // sign + 1/(hw^2 b) folded in
    scratch[t] = s;
    __syncthreads();
    for (int off = 128; off > 0; off >>= 1) {
        if (t < off) scratch[t] += scratch[t + off];
        __syncthreads();
    }
    if (t == 0) partial[blockIdx.x] = scratch[0];
}

// ---------------- final combine: 184 scalars -> 4 outputs ------------------
__global__ void finish_kernel(const float* __restrict__ partial,
                              float* __restrict__ out)
{
    int t = threadIdx.x;   // 64 threads
    float s1 = 0.f, s2 = 0.f;
    if (t < 40) s1 = partial[t];
    for (int i = 40 + t; i < 184; i += 64) s2 += partial[i];
#pragma unroll
    for (int off = 32; off > 0; off >>= 1) {
        s1 += __shfl_down(s1, off);
        s2 += __shfl_down(s2, off);
    }
    if (t == 0) {
        float l = s1 + s2;
        out[0] = l;        // loss
        out[1] = l;        // stack[0]
        out[2] = s1;       // stack[1] = pwl_g1
        out[3] = s2;       // stack[2] = pwl_g2
    }
}

extern "C" void kernel_launch(void* const* d_in, const int* in_sizes, int n_in,
                              void* d_out, int out_size, void* d_ws, size_t ws_size,
                              hipStream_t stream)
{
    const float* x1t = (const float*)d_in[0];   // [4,128,64,64]
    const float* x1s = (const float*)d_in[1];
    const float* x2t = (const float*)d_in[2];   // [4,256,32,32]
    const float* x2s = (const float*)d_in[3];

    float* ws      = (float*)d_ws;
    float* invn    = ws;             // 40960 floats
    float* partial = ws + 40960;     // 184 floats (fully overwritten each call)

    norm_kernel<<<320, 256, 0, stream>>>(x1t, x1s, x2t, x2s, invn);
    gramfrob_kernel<<<184, 256, 0, stream>>>(x1t, x1s, x2t, x2s, invn, partial);
    finish_kernel<<<1, 64, 0, stream>>>(partial, (float*)d_out);
}

// Round 4
// 132.581 us; speedup vs baseline: 5.8731x; 1.0544x over previous
//
#include <hip/hip_runtime.h>
#include <math.h>

#define EPSF 1e-8f

typedef __attribute__((ext_vector_type(4))) short short4v;
typedef __attribute__((ext_vector_type(8))) short short8v;
typedef __attribute__((ext_vector_type(4))) float float4v;

__device__ inline short f2bf(float f) {
    unsigned u = __builtin_bit_cast(unsigned, f);
    unsigned r = (u + 0x7FFFu + ((u >> 16) & 1u)) >> 16;
    return (short)r;
}

// F layout (bf16 shorts): f1t @0 (4*128*4096), f1s @2097152, f2t @4194304
// (4*256*1024), f2s @5242880; total 6291456 shorts = 12.6 MB.
#define F1T 0
#define F1S 2097152
#define F2T 4194304
#define F2S 5242880

// sub-tile tables: {g, ra64, rb64, wtcode}. g: 0=t*t 1=s*s 2=t*s.
// Diagonal grams are symmetric: upper triangle only, off-diag doubled.
__constant__ int g1_tab[10][4] = {
    {0,0,0,1},{0,0,1,2},{0,1,1,1},
    {1,0,0,1},{1,0,1,2},{1,1,1,1},
    {2,0,0,-2},{2,0,1,-2},{2,1,0,-2},{2,1,1,-2},
};
__constant__ int g2_tab[36][4] = {
    {0,0,0,1},{0,0,1,2},{0,0,2,2},{0,0,3,2},{0,1,1,1},{0,1,2,2},{0,1,3,2},{0,2,2,1},{0,2,3,2},{0,3,3,1},
    {1,0,0,1},{1,0,1,2},{1,0,2,2},{1,0,3,2},{1,1,1,1},{1,1,2,2},{1,1,3,2},{1,2,2,1},{1,2,3,2},{1,3,3,1},
    {2,0,0,-2},{2,0,1,-2},{2,0,2,-2},{2,0,3,-2},
    {2,1,0,-2},{2,1,1,-2},{2,1,2,-2},{2,1,3,-2},
    {2,2,0,-2},{2,2,1,-2},{2,2,2,-2},{2,2,3,-2},
    {2,3,0,-2},{2,3,1,-2},{2,3,2,-2},{2,3,3,-2},
};

// ------------- prep: per-pixel norm + normalize + bf16 convert -------------
// 320 blocks x 128 px. Phase 1: squares via float4, LDS-reduce -> invn[128].
// Phase 2: re-read rows (L2-hot), scale, convert, write bf16 F.
__global__ __launch_bounds__(256) void prep_kernel(
    const float* __restrict__ x1t, const float* __restrict__ x1s,
    const float* __restrict__ x2t, const float* __restrict__ x2s,
    short* __restrict__ F)
{
    int gp = blockIdx.x * 128;
    const float* x; short* f; int c, hw, base;
    if (gp < 16384)      { x = x1t; f = F + F1T; c = 128; hw = 4096; base = 0; }
    else if (gp < 32768) { x = x1s; f = F + F1S; c = 128; hw = 4096; base = 16384; }
    else if (gp < 36864) { x = x2t; f = F + F2T; c = 256; hw = 1024; base = 32768; }
    else                 { x = x2s; f = F + F2S; c = 256; hw = 1024; base = 36864; }
    const int t = threadIdx.x, lanei = t & 31, slice = t >> 5;
    int lp = gp - base + lanei * 4;      // blocks never straddle b or tensor
    int b = lp / hw, m = lp - b * hw;
    const float* p = x + (size_t)b * c * hw + m;
    short*       q = f + (size_t)b * c * hw + m;
    const int cpr = c >> 3;
    float4 s = {0.f, 0.f, 0.f, 0.f};
    for (int r = slice * cpr; r < (slice + 1) * cpr; ++r) {
        float4 v = *(const float4*)(p + (size_t)r * hw);
        s.x += v.x * v.x; s.y += v.y * v.y; s.z += v.z * v.z; s.w += v.w * v.w;
    }
    __shared__ float4 red[8][32];
    __shared__ float4 invl[32];
    red[slice][lanei] = s;
    __syncthreads();
    if (t < 32) {
        float4 tot = {0.f, 0.f, 0.f, 0.f};
#pragma unroll
        for (int sl = 0; sl < 8; ++sl) {
            float4 v = red[sl][t];
            tot.x += v.x; tot.y += v.y; tot.z += v.z; tot.w += v.w;
        }
        invl[t] = (float4){ 1.f / (sqrtf(tot.x) + EPSF), 1.f / (sqrtf(tot.y) + EPSF),
                            1.f / (sqrtf(tot.z) + EPSF), 1.f / (sqrtf(tot.w) + EPSF) };
    }
    __syncthreads();
    const float4 iv = invl[lanei];
    for (int r = slice * cpr; r < (slice + 1) * cpr; ++r) {
        float4 v = *(const float4*)(p + (size_t)r * hw);
        short4v o = { f2bf(v.x * iv.x), f2bf(v.y * iv.y),
                      f2bf(v.z * iv.z), f2bf(v.w * iv.w) };
        *(short4v*)(q + (size_t)r * hw) = o;
    }
}

// ------------- gram tile body: pure global-load -> MFMA dataflow -----------
// Fragment = 8 consecutive bf16 pixels = one aligned 16B load. No LDS.
template<int HW, int NIT, bool SHARE>
__device__ inline void gram_body(const short* __restrict__ Fa,
                                 const short* __restrict__ Fb,
                                 int k0, int lane, float4v acc[4][4])
{
    const int r16 = lane & 15, quad = lane >> 4;
    const int kb = k0 + quad * 8;
#pragma unroll
    for (int it = 0; it < NIT; ++it) {
        short8v af[4], bfr[4];
#pragma unroll
        for (int rt = 0; rt < 4; ++rt)
            af[rt] = *(const short8v*)(Fa + (size_t)(rt * 16 + r16) * HW + kb + it * 32);
        if (SHARE) {
#pragma unroll
            for (int ct = 0; ct < 4; ++ct) bfr[ct] = af[ct];
        } else {
#pragma unroll
            for (int ct = 0; ct < 4; ++ct)
                bfr[ct] = *(const short8v*)(Fb + (size_t)(ct * 16 + r16) * HW + kb + it * 32);
        }
#pragma unroll
        for (int rt = 0; rt < 4; ++rt)
#pragma unroll
            for (int ct = 0; ct < 4; ++ct)
                acc[rt][ct] = __builtin_amdgcn_mfma_f32_16x16x32_bf16(
                    af[rt], bfr[ct], acc[rt][ct], 0, 0, 0);
    }
}

// ------------- gram-Frobenius: 184 blocks x 512 thr (8-way k-split) --------
__global__ __launch_bounds__(512) void gramfrob_kernel(
    const short* __restrict__ F, float* __restrict__ partial)
{
    __shared__ float buf[2][64 * 68];   // stride-68: 2-way banks (free)
    __shared__ float scratch[512];

    const int id = blockIdx.x;
    const int t = threadIdx.x, w = t >> 6, lane = t & 63;
    const int r16 = lane & 15, quad = lane >> 4;

    float4v acc[4][4];
#pragma unroll
    for (int i = 0; i < 4; ++i)
#pragma unroll
        for (int j = 0; j < 4; ++j) acc[i][j] = (float4v){0.f, 0.f, 0.f, 0.f};

    float wt;
    if (id < 40) {
        const int comb = id >> 2, b = id & 3;
        const int g = g1_tab[comb][0];
        const int ra = g1_tab[comb][1] << 6, rb = g1_tab[comb][2] << 6;
        wt = (float)g1_tab[comb][3] * (1.0f / (4096.f * 4096.f * 4.f));
        const short* xt = F + F1T; const short* xs = F + F1S;
        const short* Fa = ((g == 1) ? xs : xt) + (size_t)(b * 128 + ra) * 4096;
        const short* Fb = ((g == 0) ? xt : xs) + (size_t)(b * 128 + rb) * 4096;
        const int k0 = w * 512;
        if (g < 2 && ra == rb) gram_body<4096, 16, true >(Fa, Fa, k0, lane, acc);
        else                   gram_body<4096, 16, false>(Fa, Fb, k0, lane, acc);
    } else {
        const int id2 = id - 40;
        const int comb = id2 >> 2, b = id2 & 3;
        const int g = g2_tab[comb][0];
        const int ra = g2_tab[comb][1] << 6, rb = g2_tab[comb][2] << 6;
        wt = (float)g2_tab[comb][3] * (1.0f / (1024.f * 1024.f * 4.f));
        const short* xt = F + F2T; const short* xs = F + F2S;
        const short* Fa = ((g == 1) ? xs : xt) + (size_t)(b * 256 + ra) * 1024;
        const short* Fb = ((g == 0) ? xt : xs) + (size_t)(b * 256 + rb) * 1024;
        const int k0 = w * 128;
        if (g < 2 && ra == rb) gram_body<1024, 4, true >(Fa, Fa, k0, lane, acc);
        else                   gram_body<1024, 4, false>(Fa, Fb, k0, lane, acc);
    }

    // ---- combine 8 wave partials (4 rounds, 2 buffers), square, reduce ----
    // C/D layout: col = lane&15, row = quad*4 + reg.
#pragma unroll 1
    for (int rr = 0; rr < 4; ++rr) {
        if ((w >> 1) == rr) {
            float* dst = buf[w & 1];
#pragma unroll
            for (int rt = 0; rt < 4; ++rt)
#pragma unroll
                for (int ct = 0; ct < 4; ++ct)
#pragma unroll
                    for (int r = 0; r < 4; ++r) {
                        int off = (rt * 16 + quad * 4 + r) * 68 + ct * 16 + r16;
                        if (rr == 0) dst[off] = acc[rt][ct][r];
                        else         dst[off] += acc[rt][ct][r];
                    }
        }
        __syncthreads();
    }
    float s = 0.f;
#pragma unroll
    for (int i = 0; i < 8; ++i) {
        int cell = (i << 9) + t;
        int off = (cell >> 6) * 68 + (cell & 63);
        float v = buf[0][off] + buf[1][off];
        s += v * v;
    }
    s *= wt;                             // sign + 1/(hw^2 * b) folded in
    scratch[t] = s;
    __syncthreads();
    for (int off = 256; off > 0; off >>= 1) {
        if (t < off) scratch[t] += scratch[t + off];
        __syncthreads();
    }
    if (t == 0) partial[blockIdx.x] = scratch[0];
}

// ---------------- final combine: 184 scalars -> 4 outputs ------------------
__global__ void finish_kernel(const float* __restrict__ partial,
                              float* __restrict__ out)
{
    int t = threadIdx.x;   // 64 threads
    float s1 = 0.f, s2 = 0.f;
    if (t < 40) s1 = partial[t];
    for (int i = 40 + t; i < 184; i += 64) s2 += partial[i];
#pragma unroll
    for (int off = 32; off > 0; off >>= 1) {
        s1 += __shfl_down(s1, off);
        s2 += __shfl_down(s2, off);
    }
    if (t == 0) {
        float l = s1 + s2;
        out[0] = l;        // loss
        out[1] = l;        // stack[0]
        out[2] = s1;       // stack[1] = pwl_g1
        out[3] = s2;       // stack[2] = pwl_g2
    }
}

extern "C" void kernel_launch(void* const* d_in, const int* in_sizes, int n_in,
                              void* d_out, int out_size, void* d_ws, size_t ws_size,
                              hipStream_t stream)
{
    const float* x1t = (const float*)d_in[0];   // [4,128,64,64]
    const float* x1s = (const float*)d_in[1];
    const float* x2t = (const float*)d_in[2];   // [4,256,32,32]
    const float* x2s = (const float*)d_in[3];

    short* F       = (short*)d_ws;               // 6291456 shorts (12.6 MB)
    float* partial = (float*)d_ws + 3200000;     // 184 floats, fully rewritten

    prep_kernel<<<320, 256, 0, stream>>>(x1t, x1s, x2t, x2s, F);
    gramfrob_kernel<<<184, 512, 0, stream>>>(F, partial);
    finish_kernel<<<1, 64, 0, stream>>>(partial, (float*)d_out);
}

// Round 5
// 119.108 us; speedup vs baseline: 6.5374x; 1.1131x over previous
//
#include <hip/hip_runtime.h>
#include <math.h>

#define EPSF 1e-8f

typedef __attribute__((ext_vector_type(4))) short short4v;
typedef __attribute__((ext_vector_type(8))) short short8v;
typedef __attribute__((ext_vector_type(4))) float float4v;

__device__ inline short f2bf(float f) {
    unsigned u = __builtin_bit_cast(unsigned, f);
    unsigned r = (u + 0x7FFFu + ((u >> 16) & 1u)) >> 16;
    return (short)r;
}

// F layout (bf16 shorts): f1t @0 (4*128*4096), f1s @2097152, f2t @4194304
// (4*256*1024), f2s @5242880; total 6291456 shorts = 12.6 MB.
#define F1T 0
#define F1S 2097152
#define F2T 4194304
#define F2S 5242880

// 36 sub-tile combos per group: {g, ri, rj, w}. g: 0=t*t 1=s*s 2=t*s.
// Diagonal grams symmetric: upper triangle; diag w=1, off-diag w=2; cross w=-2.
// Tile unit = 32 rows (group1, c=128 -> 4x4 grid) or 64 rows (group2, c=256).
__constant__ int tab[36][4] = {
    {0,0,0,1},{0,0,1,2},{0,0,2,2},{0,0,3,2},{0,1,1,1},{0,1,2,2},{0,1,3,2},{0,2,2,1},{0,2,3,2},{0,3,3,1},
    {1,0,0,1},{1,0,1,2},{1,0,2,2},{1,0,3,2},{1,1,1,1},{1,1,2,2},{1,1,3,2},{1,2,2,1},{1,2,3,2},{1,3,3,1},
    {2,0,0,-2},{2,0,1,-2},{2,0,2,-2},{2,0,3,-2},
    {2,1,0,-2},{2,1,1,-2},{2,1,2,-2},{2,1,3,-2},
    {2,2,0,-2},{2,2,1,-2},{2,2,2,-2},{2,2,3,-2},
    {2,3,0,-2},{2,3,1,-2},{2,3,2,-2},{2,3,3,-2},
};

// ------------- prep: per-pixel norm + normalize + bf16 convert -------------
__global__ __launch_bounds__(256) void prep_kernel(
    const float* __restrict__ x1t, const float* __restrict__ x1s,
    const float* __restrict__ x2t, const float* __restrict__ x2s,
    short* __restrict__ F)
{
    int gp = blockIdx.x * 128;
    const float* x; short* f; int c, hw, base;
    if (gp < 16384)      { x = x1t; f = F + F1T; c = 128; hw = 4096; base = 0; }
    else if (gp < 32768) { x = x1s; f = F + F1S; c = 128; hw = 4096; base = 16384; }
    else if (gp < 36864) { x = x2t; f = F + F2T; c = 256; hw = 1024; base = 32768; }
    else                 { x = x2s; f = F + F2S; c = 256; hw = 1024; base = 36864; }
    const int t = threadIdx.x, lanei = t & 31, slice = t >> 5;
    int lp = gp - base + lanei * 4;      // blocks never straddle b or tensor
    int b = lp / hw, m = lp - b * hw;
    const float* p = x + (size_t)b * c * hw + m;
    short*       q = f + (size_t)b * c * hw + m;
    const int cpr = c >> 3;
    float4 s = {0.f, 0.f, 0.f, 0.f};
    for (int r = slice * cpr; r < (slice + 1) * cpr; ++r) {
        float4 v = *(const float4*)(p + (size_t)r * hw);
        s.x += v.x * v.x; s.y += v.y * v.y; s.z += v.z * v.z; s.w += v.w * v.w;
    }
    __shared__ float4 red[8][32];
    __shared__ float4 invl[32];
    red[slice][lanei] = s;
    __syncthreads();
    if (t < 32) {
        float4 tot = {0.f, 0.f, 0.f, 0.f};
#pragma unroll
        for (int sl = 0; sl < 8; ++sl) {
            float4 v = red[sl][t];
            tot.x += v.x; tot.y += v.y; tot.z += v.z; tot.w += v.w;
        }
        invl[t] = (float4){ 1.f / (sqrtf(tot.x) + EPSF), 1.f / (sqrtf(tot.y) + EPSF),
                            1.f / (sqrtf(tot.z) + EPSF), 1.f / (sqrtf(tot.w) + EPSF) };
    }
    __syncthreads();
    const float4 iv = invl[lanei];
    for (int r = slice * cpr; r < (slice + 1) * cpr; ++r) {
        float4 v = *(const float4*)(p + (size_t)r * hw);
        short4v o = { f2bf(v.x * iv.x), f2bf(v.y * iv.y),
                      f2bf(v.z * iv.z), f2bf(v.w * iv.w) };
        *(short4v*)(q + (size_t)r * hw) = o;
    }
}

// ------------- gram tile body: global-load -> MFMA, bounded unroll ---------
template<int HW, int NIT, int NF, bool SHARE>
__device__ inline void gram_body(const short* __restrict__ Fa,
                                 const short* __restrict__ Fb,
                                 int k0, int lane, float4v (&acc)[NF][NF])
{
    const int r16 = lane & 15, quad = lane >> 4;
    const int kb = k0 + quad * 8;
#pragma unroll 2
    for (int it = 0; it < NIT; ++it) {
        short8v af[NF], bfr[NF];
#pragma unroll
        for (int rt = 0; rt < NF; ++rt)
            af[rt] = *(const short8v*)(Fa + (size_t)(rt * 16 + r16) * HW + kb + it * 32);
        if (SHARE) {
#pragma unroll
            for (int ct = 0; ct < NF; ++ct) bfr[ct] = af[ct];
        } else {
#pragma unroll
            for (int ct = 0; ct < NF; ++ct)
                bfr[ct] = *(const short8v*)(Fb + (size_t)(ct * 16 + r16) * HW + kb + it * 32);
        }
#pragma unroll
        for (int rt = 0; rt < NF; ++rt)
#pragma unroll
            for (int ct = 0; ct < NF; ++ct)
                acc[rt][ct] = __builtin_amdgcn_mfma_f32_16x16x32_bf16(
                    af[rt], bfr[ct], acc[rt][ct], 0, 0, 0);
    }
}

// ------------- epilogue: combine 8 wave partials, square, weight -----------
template<int TILE, int NF>
__device__ inline float epilogue(float4v (&acc)[NF][NF], float* buf,
                                 int t, int w, int lane, float wt)
{
    const int r16 = lane & 15, quad = lane >> 4;
    constexpr int STR = TILE + 4;        // 2-way bank alias only (free)
    constexpr int BUFSZ = TILE * STR;
#pragma unroll 1
    for (int rr = 0; rr < 4; ++rr) {
        if ((w >> 1) == rr) {
            float* dst = buf + (w & 1) * BUFSZ;
#pragma unroll
            for (int rt = 0; rt < NF; ++rt)
#pragma unroll
                for (int ct = 0; ct < NF; ++ct)
#pragma unroll
                    for (int r = 0; r < 4; ++r) {
                        int off = (rt * 16 + quad * 4 + r) * STR + ct * 16 + r16;
                        if (rr == 0) dst[off] = acc[rt][ct][r];
                        else         dst[off] += acc[rt][ct][r];
                    }
        }
        __syncthreads();
    }
    float s = 0.f;
#pragma unroll
    for (int i = 0; i < (TILE * TILE) / 512; ++i) {
        int cell = (i << 9) + t;
        int off = (cell / TILE) * STR + (cell & (TILE - 1));
        float v = buf[off] + buf[BUFSZ + off];
        s += v * v;
    }
    return s * wt;
}

// ------------- gram-Frobenius: 288 uniform blocks x 512 threads ------------
// Every block: 4.19M MACs = 512 MFMAs (g1: 32x32 tile, k=4096; g2: 64x64,
// k=1024), 8-way k-split across waves, no global atomics, no memsets.
__global__ __launch_bounds__(512) void gramfrob_kernel(
    const short* __restrict__ F, float* __restrict__ partial)
{
    __shared__ __align__(16) char lds[36864];
    float* buf     = (float*)lds;                // up to 2 x 64x68 floats
    float* scratch = (float*)(lds + 34816);      // 512 floats

    const int id = blockIdx.x;
    const int t = threadIdx.x, w = t >> 6, lane = t & 63;

    float s;
    if (id < 144) {                              // group 1: c=128, hw=4096
        const int comb = id >> 2, b = id & 3;
        const int g = tab[comb][0];
        const int ra = tab[comb][1] << 5, rb = tab[comb][2] << 5;
        const float wt = (float)tab[comb][3] * (1.0f / (4096.f * 4096.f * 4.f));
        const short* Fa = (g == 1 ? F + F1S : F + F1T) + (size_t)(b * 128 + ra) * 4096;
        const short* Fb = (g == 0 ? F + F1T : F + F1S) + (size_t)(b * 128 + rb) * 4096;
        float4v acc[2][2];
#pragma unroll
        for (int i = 0; i < 2; ++i)
#pragma unroll
            for (int j = 0; j < 2; ++j) acc[i][j] = (float4v){0.f, 0.f, 0.f, 0.f};
        const int k0 = w * 512;
        if (g < 2 && ra == rb) gram_body<4096, 16, 2, true >(Fa, Fa, k0, lane, acc);
        else                   gram_body<4096, 16, 2, false>(Fa, Fb, k0, lane, acc);
        s = epilogue<32, 2>(acc, buf, t, w, lane, wt);
    } else {                                     // group 2: c=256, hw=1024
        const int id2 = id - 144;
        const int comb = id2 >> 2, b = id2 & 3;
        const int g = tab[comb][0];
        const int ra = tab[comb][1] << 6, rb = tab[comb][2] << 6;
        const float wt = (float)tab[comb][3] * (1.0f / (1024.f * 1024.f * 4.f));
        const short* Fa = (g == 1 ? F + F2S : F + F2T) + (size_t)(b * 256 + ra) * 1024;
        const short* Fb = (g == 0 ? F + F2T : F + F2S) + (size_t)(b * 256 + rb) * 1024;
        float4v acc[4][4];
#pragma unroll
        for (int i = 0; i < 4; ++i)
#pragma unroll
            for (int j = 0; j < 4; ++j) acc[i][j] = (float4v){0.f, 0.f, 0.f, 0.f};
        const int k0 = w * 128;
        if (g < 2 && ra == rb) gram_body<1024, 4, 4, true >(Fa, Fa, k0, lane, acc);
        else                   gram_body<1024, 4, 4, false>(Fa, Fb, k0, lane, acc);
        s = epilogue<64, 4>(acc, buf, t, w, lane, wt);
    }

    scratch[t] = s;
    __syncthreads();
    for (int off = 256; off > 0; off >>= 1) {
        if (t < off) scratch[t] += scratch[t + off];
        __syncthreads();
    }
    if (t == 0) partial[blockIdx.x] = scratch[0];
}

// ---------------- final combine: 288 scalars -> 4 outputs ------------------
__global__ void finish_kernel(const float* __restrict__ partial,
                              float* __restrict__ out)
{
    int t = threadIdx.x;   // 64 threads
    float s1 = 0.f, s2 = 0.f;
    for (int i = t; i < 144; i += 64) s1 += partial[i];
    for (int i = 144 + t; i < 288; i += 64) s2 += partial[i];
#pragma unroll
    for (int off = 32; off > 0; off >>= 1) {
        s1 += __shfl_down(s1, off);
        s2 += __shfl_down(s2, off);
    }
    if (t == 0) {
        float l = s1 + s2;
        out[0] = l;        // loss
        out[1] = l;        // stack[0]
        out[2] = s1;       // stack[1] = pwl_g1
        out[3] = s2;       // stack[2] = pwl_g2
    }
}

extern "C" void kernel_launch(void* const* d_in, const int* in_sizes, int n_in,
                              void* d_out, int out_size, void* d_ws, size_t ws_size,
                              hipStream_t stream)
{
    const float* x1t = (const float*)d_in[0];   // [4,128,64,64]
    const float* x1s = (const float*)d_in[1];
    const float* x2t = (const float*)d_in[2];   // [4,256,32,32]
    const float* x2s = (const float*)d_in[3];

    short* F       = (short*)d_ws;               // 6291456 shorts (12.6 MB)
    float* partial = (float*)d_ws + 3200000;     // 288 floats, fully rewritten

    prep_kernel<<<320, 256, 0, stream>>>(x1t, x1s, x2t, x2s, F);
    gramfrob_kernel<<<288, 512, 0, stream>>>(F, partial);
    finish_kernel<<<1, 64, 0, stream>>>(partial, (float*)d_out);
}